// Round 12
// baseline (6731.624 us; speedup 1.0000x reference)
//
#include <hip/hip_runtime.h>
#include <hip/hip_bf16.h>
#include <cstdint>
#include <cstddef>

#define NB 65536
#define DD 512
#define HH 1024

typedef __attribute__((ext_vector_type(8))) short short8;
typedef __attribute__((ext_vector_type(4))) short short4v;
typedef __attribute__((ext_vector_type(4))) float f32x4;
typedef __attribute__((ext_vector_type(4))) int int4v;

__device__ __forceinline__ float bf2f(short s){
  union { float f; unsigned u; } v; v.u = ((unsigned)(unsigned short)s) << 16; return v.f;
}
__device__ __forceinline__ short f2bf(float f){
  union { float f; unsigned u; } v; v.f = f;
  unsigned u = v.u;
  u += 0x7FFFu + ((u >> 16) & 1u);
  return (short)(u >> 16);
}
__device__ __forceinline__ float sigm(float x){ return 1.0f / (1.0f + __expf(-x)); }

// sum over the 16 lanes of a DPP row; result in all lanes
__device__ __forceinline__ float rowsum16(float v){
  int x;
  x = __builtin_amdgcn_update_dpp(0, __float_as_int(v), 0x128, 0xF, 0xF, true); v += __int_as_float(x); // ror:8
  x = __builtin_amdgcn_update_dpp(0, __float_as_int(v), 0x124, 0xF, 0xF, true); v += __int_as_float(x); // ror:4
  x = __builtin_amdgcn_update_dpp(0, __float_as_int(v), 0x122, 0xF, 0xF, true); v += __int_as_float(x); // ror:2
  x = __builtin_amdgcn_update_dpp(0, __float_as_int(v), 0x121, 0xF, 0xF, true); v += __int_as_float(x); // ror:1
  return v;
}

// XCD-bijective remap: each XCD gets a contiguous m-range; the NX (n/j)-blocks
// sharing one A-tile run consecutively on the same XCD -> A-tile L2 reuse.
__device__ __forceinline__ int2 xcd_remap(int NX, int G){
  int flat = blockIdx.y*NX + blockIdx.x;
  int l = (flat & 7)*(G>>3) + (flat>>3);
  return make_int2(l / NX, l % NX);   // (m-tile, xj)
}

#define GLL(srcp, dstp) \
  __builtin_amdgcn_global_load_lds((const __attribute__((address_space(1))) void*)(srcp), \
                                   (__attribute__((address_space(3))) void*)(dstp), 16, 0, 0)

// ---- swizzled stage of a 128x32 bf16 tile into LDS as [64 phys rows][128B],
// logical rows 0-63 in granules 0-3, rows 64-127 in granules 4-7, with
// granule XOR (p&7).  Linear GLL dest; swizzle folded into global source.
// (4-wave variant, used by hebb-free 256-thread kernels if needed)
__device__ __forceinline__ void stage128x32s(const short* __restrict__ g, int row0, int ldk, int k0,
                                             short* lds_base, int wave, int lane){
  const int pl = lane>>3, Gp = lane&7;
  const int Gl = Gp ^ pl;
  const int rconst = pl + ((Gl>>2)<<6);
  const int kg = (Gl&3)*8;
#pragma unroll
  for (int i = 0; i < 2; ++i){
    int c = wave*2 + i;
    const short* src = g + (size_t)(row0 + c*8 + rconst)*(size_t)ldk + (size_t)(k0 + kg);
    GLL(src, lds_base + c*512);
  }
}

// ---- i8 variant: 128x64 i8 tile (same 8 KB byte-shape), ldk fixed 512 B
__device__ __forceinline__ void stage128x64q(const char* __restrict__ g, int k0B,
                                             char* lds_base, int wave, int lane){
  const int pl = lane>>3, Gp = lane&7;
  const int Gl = Gp ^ pl;
  const int rconst = pl + ((Gl>>2)<<6);
  const int kg = (Gl&3)*16;
#pragma unroll
  for (int i = 0; i < 2; ++i){
    int c = wave*2 + i;
    const char* src = g + (size_t)(c*8 + rconst)*512 + (size_t)(k0B + kg);
    GLL(src, lds_base + c*1024);
  }
}

// ============================================================================
// 256x128-tile NT GEMM core: BK=32, double-buffered LDS (48 KB), 8 waves
// (4M x 2N, per-wave 64x64 acc[4][4]); vmcnt(0)+barrier per K-step hidden by
// 3 blocks/CU x 8 waves = 24 waves/CU TLP.  Same [64 phys rows][128B]
// granule^(row&7) swizzle as the verified 128² core; 24 stage chunks of 1 KB
// assigned 3 per wave.  C[m,n] = sum_k A[m,k]*W[n,k], A/W bf16 row-major.
// LDS layout (shorts): A0 [0,4096) A1 [4096,8192) B [8192,12288) per buffer.
// ============================================================================
template<int KTOT>
__device__ __forceinline__ void gemm256x128(const short* __restrict__ A, const short* __restrict__ W,
        int m0, int n0, short* smem, f32x4 acc[4][4], int wave, int lane)
{
  const int lr = lane & 15, lq = lane>>4;
  const int wm = wave>>1, wn = wave&1;
  const int aTile = (wm>>1)*4096;        // wm 0,1 -> A0 ; 2,3 -> A1
  const int hiA = wm&1;
  int aOff[4], bOff[4];
#pragma unroll
  for (int i=0;i<4;++i){
    int pa = i*16 + lr;
    aOff[i] = aTile + pa*64 + (((hiA*4+lq) ^ (pa&7))<<3);
    bOff[i] = 8192  + pa*64 + (((wn*4+lq) ^ (pa&7))<<3);
  }
  // stage source addressing: 3 chunks per wave (chunks 0-7=A0, 8-15=A1, 16-23=B)
  const int pl = lane>>3, Gp = lane&7;
  const int Gl = Gp ^ pl;
  const int rconst = pl + ((Gl>>2)<<6);
  const int kg = (Gl&3)*8;
  const short* srcb[3]; int ldso[3];
#pragma unroll
  for (int k=0;k<3;++k){
    int chunk = wave*3 + k;
    int t = chunk>>3, ci = chunk&7;
    const short* base;
    if (t == 0)      base = A + (size_t)(m0       + ci*8 + rconst)*KTOT + kg;
    else if (t == 1) base = A + (size_t)(m0 + 128 + ci*8 + rconst)*KTOT + kg;
    else             base = W + (size_t)(n0       + ci*8 + rconst)*KTOT + kg;
    srcb[k] = base;
    ldso[k] = t*4096 + ci*512;
  }

  {
    short* b0 = smem;
#pragma unroll
    for (int k=0;k<3;++k) GLL(srcb[k], b0 + ldso[k]);
  }
  asm volatile("s_waitcnt vmcnt(0)" ::: "memory");
  __builtin_amdgcn_s_barrier();
  int cur = 0;
#pragma unroll
  for (int k0 = 0; k0 < KTOT; k0 += 32){
    short* buf  = smem + cur*12288;
    short* nbuf = smem + (cur^1)*12288;
    if (k0 + 32 < KTOT){
#pragma unroll
      for (int k=0;k<3;++k) GLL(srcb[k] + (k0+32), nbuf + ldso[k]);
    }
    short8 af[4], bf[4];
#pragma unroll
    for (int i=0;i<4;++i) af[i] = *(const short8*)&buf[aOff[i]];
#pragma unroll
    for (int i=0;i<4;++i) bf[i] = *(const short8*)&buf[bOff[i]];
    __builtin_amdgcn_s_setprio(1);
#pragma unroll
    for (int mi=0;mi<4;++mi)
#pragma unroll
      for (int ni=0;ni<4;++ni)
        acc[mi][ni] = __builtin_amdgcn_mfma_f32_16x16x32_bf16(af[mi], bf[ni], acc[mi][ni], 0, 0, 0);
    __builtin_amdgcn_s_setprio(0);
    asm volatile("s_waitcnt vmcnt(0)" ::: "memory");
    __builtin_amdgcn_s_barrier();
    cur ^= 1;
  }
}

#define ZERO_ACC(acc) \
  _Pragma("unroll") for (int zi=0;zi<4;++zi) _Pragma("unroll") for (int zj=0;zj<4;++zj) \
    acc[zi][zj] = (f32x4){0.f,0.f,0.f,0.f};

// ---- CMS level GEMM1: H = relu(out @ w1^T + b1), bf16 out. N=1024, K=512
__global__ __launch_bounds__(512, 6) void k_gemm_h(const int* __restrict__ gs, int freq,
     const short* __restrict__ A, const short* __restrict__ W1, const float* __restrict__ b1,
     short* __restrict__ Hout)
{
  if (gs[0] % freq) return;
  __shared__ __align__(16) short smem[24576];
  const int tid = threadIdx.x, wave = tid>>6, lane = tid&63;
  const int wm = wave>>1, wn = wave&1, lr = lane&15, lq = lane>>4;
  int2 r = xcd_remap(8, 2048);
  const int m0 = r.x*256, n0 = r.y*128;
  f32x4 acc[4][4]; ZERO_ACC(acc);
  gemm256x128<DD>(A, W1, m0, n0, smem, acc, wave, lane);
  const int rbase = m0 + wm*64 + lq*4;
  const int cbase = n0 + wn*64 + lr;
#pragma unroll
  for (int ni=0;ni<4;++ni){
    const float bias = b1[cbase + ni*16];
#pragma unroll
    for (int mi=0;mi<4;++mi)
#pragma unroll
      for (int rr=0;rr<4;++rr){
        float v = acc[mi][ni][rr] + bias;
        v = v > 0.f ? v : 0.f;
        Hout[(size_t)(rbase + mi*16 + rr)*HH + (cbase + ni*16)] = f2bf(v);
      }
  }
}

// ---- CMS level GEMM2: out += H @ w2^T + b2, bf16 in-place residual. N=512, K=1024
__global__ __launch_bounds__(512, 6) void k_gemm_res(const int* __restrict__ gs, int freq,
     const short* __restrict__ Hb, const short* __restrict__ W2, const float* __restrict__ b2,
     short* __restrict__ outb)
{
  if (gs[0] % freq) return;
  __shared__ __align__(16) short smem[24576];
  const int tid = threadIdx.x, wave = tid>>6, lane = tid&63;
  const int wm = wave>>1, wn = wave&1, lr = lane&15, lq = lane>>4;
  int2 r = xcd_remap(4, 1024);
  const int m0 = r.x*256, n0 = r.y*128;
  f32x4 acc[4][4]; ZERO_ACC(acc);
  gemm256x128<HH>(Hb, W2, m0, n0, smem, acc, wave, lane);
  const int rbase = m0 + wm*64 + lq*4;
  const int cbase = n0 + wn*64 + lr;
#pragma unroll
  for (int ni=0;ni<4;++ni){
    const float bias = b2[cbase + ni*16];
#pragma unroll
    for (int mi=0;mi<4;++mi)
#pragma unroll
      for (int rr=0;rr<4;++rr){
        size_t off = (size_t)(rbase + mi*16 + rr)*DD + (cbase + ni*16);
        float v = acc[mi][ni][rr] + bias + bf2f(outb[off]);
        outb[off] = f2bf(v);
      }
  }
}

// ---- per-row int8 quantization of x_cms (bf16 -> i8 + row scale)
__global__ __launch_bounds__(256) void k_quantx(const short* __restrict__ outb,
     char* __restrict__ x8, float* __restrict__ sxr)
{
  const int tid = threadIdx.x, wave = tid>>6, lane = tid&63;
  const int row = blockIdx.x*4 + wave;
  short8 v = *(const short8*)&outb[(size_t)row*DD + lane*8];
  float f[8]; float m = 0.f;
#pragma unroll
  for (int j=0;j<8;++j){ f[j] = bf2f(v[j]); m = fmaxf(m, fabsf(f[j])); }
#pragma unroll
  for (int off=32; off; off>>=1) m = fmaxf(m, __shfl_xor(m, off));
  m = fmaxf(m, 1e-20f);
  const float inv = 127.0f / m;
  unsigned lo=0, hi=0;
#pragma unroll
  for (int j=0;j<4;++j){ int q=(int)rintf(f[j]*inv); q=q>127?127:(q<-127?-127:q); lo |= ((unsigned)(q&255))<<(8*j); }
#pragma unroll
  for (int j=0;j<4;++j){ int q=(int)rintf(f[4+j]*inv); q=q>127?127:(q<-127?-127:q); hi |= ((unsigned)(q&255))<<(8*j); }
  int2 w; w.x=(int)lo; w.y=(int)hi;
  *(int2*)&x8[(size_t)row*DD + lane*8] = w;
  if (lane==0) sxr[row] = m * (1.0f/127.0f);
}

// ---- per-row int8 quantization of the 3 gate weights (fp32 -> i8 + scale)
__global__ __launch_bounds__(256) void k_quantw(const float* __restrict__ gmw,
     const float* __restrict__ gsw, const float* __restrict__ ggw,
     char* __restrict__ W8, float* __restrict__ swr)
{
  const int tid = threadIdx.x, wave = tid>>6, lane = tid&63;
  const int row = blockIdx.x*4 + wave;      // 0..3071
  const int j = row >> 10;
  const float* src = (j==0?gmw:(j==1?gsw:ggw)) + (size_t)(row&1023)*DD + lane*8;
  f32x4 a = *(const f32x4*)&src[0];
  f32x4 b = *(const f32x4*)&src[4];
  float f[8] = {a[0],a[1],a[2],a[3],b[0],b[1],b[2],b[3]};
  float m = 0.f;
#pragma unroll
  for (int k=0;k<8;++k) m = fmaxf(m, fabsf(f[k]));
#pragma unroll
  for (int off=32; off; off>>=1) m = fmaxf(m, __shfl_xor(m, off));
  m = fmaxf(m, 1e-20f);
  const float inv = 127.0f / m;
  unsigned lo=0, hi=0;
#pragma unroll
  for (int k=0;k<4;++k){ int q=(int)rintf(f[k]*inv); q=q>127?127:(q<-127?-127:q); lo |= ((unsigned)(q&255))<<(8*k); }
#pragma unroll
  for (int k=0;k<4;++k){ int q=(int)rintf(f[4+k]*inv); q=q>127?127:(q<-127?-127:q); hi |= ((unsigned)(q&255))<<(8*k); }
  int2 w; w.x=(int)lo; w.y=(int)hi;
  *(int2*)&W8[(size_t)row*DD + lane*8] = w;
  if (lane==0) swr[row] = m * (1.0f/127.0f);
}

// ---- gates fused with gate-out, INT8 core (mfma_i32_16x16x64_i8, 2x bf16 rate).
__global__ __launch_bounds__(256, 4) void k_gates(const char* __restrict__ X8, const char* __restrict__ W8,
     const float* __restrict__ sxr, const float* __restrict__ swr,
     const float* __restrict__ bm, const float* __restrict__ bs, const float* __restrict__ bg,
     const float* __restrict__ gow, float* __restrict__ pacc)
{
  __shared__ __align__(16) char smemc[32768];
  __shared__ float sred[2][128][3];
  const int tid = threadIdx.x, wave = tid>>6, lane = tid&63;
  const int wmh = wave>>1, wnh = wave&1, lr = lane&15, lq = lane>>4;
  int2 r = xcd_remap(24, 12288);
  const int m0 = r.x*128, xj = r.y;
  const int j = xj >> 3;
  const int n0 = (xj & 7)*128;
  int aOff[4], bOff[4];
#pragma unroll
  for (int i=0;i<4;++i){
    int pa = i*16 + lr;
    aOff[i] =        pa*128 + (((wmh*4+lq) ^ (pa&7))<<4);
    bOff[i] = 8192 + pa*128 + (((wnh*4+lq) ^ (pa&7))<<4);
  }
  const char* aS = X8 + (size_t)m0*DD;
  const char* bS = W8 + (size_t)xj*128*DD;
  int4v acc[4][4];
#pragma unroll
  for (int zi=0;zi<4;++zi)
#pragma unroll
    for (int zj=0;zj<4;++zj) acc[zi][zj] = (int4v){0,0,0,0};

  stage128x64q(aS, 0, smemc,        wave, lane);
  stage128x64q(bS, 0, smemc + 8192, wave, lane);
  asm volatile("s_waitcnt vmcnt(0)" ::: "memory");
  __builtin_amdgcn_s_barrier();
  int cur = 0;
#pragma unroll
  for (int kt = 0; kt < 8; ++kt){
    char* buf  = smemc + cur*16384;
    char* nbuf = smemc + (cur^1)*16384;
    if (kt + 1 < 8){
      stage128x64q(aS, (kt+1)*64, nbuf,        wave, lane);
      stage128x64q(bS, (kt+1)*64, nbuf + 8192, wave, lane);
    }
    int4v af[4], bf[4];
#pragma unroll
    for (int i=0;i<4;++i) af[i] = *(const int4v*)&buf[aOff[i]];
#pragma unroll
    for (int i=0;i<4;++i) bf[i] = *(const int4v*)&buf[bOff[i]];
    __builtin_amdgcn_s_setprio(1);
#pragma unroll
    for (int mi=0;mi<4;++mi)
#pragma unroll
      for (int ni=0;ni<4;++ni)
        acc[mi][ni] = __builtin_amdgcn_mfma_i32_16x16x64_i8(af[mi], bf[ni], acc[mi][ni], 0, 0, 0);
    __builtin_amdgcn_s_setprio(0);
    asm volatile("s_waitcnt vmcnt(0)" ::: "memory");
    __builtin_amdgcn_s_barrier();
    cur ^= 1;
  }

  const int cb = n0 + wnh*64 + lr;
  const int rbase = m0 + wmh*64 + lq*4;
  const float* bj = (j==0) ? bm : ((j==1) ? bs : bg);
  float gw0[4], gw1[4], gw2[4], bias[4], sw[4];
#pragma unroll
  for (int nf=0;nf<4;++nf){
    gw0[nf]  = gow[cb + nf*16];
    gw1[nf]  = gow[1024 + cb + nf*16];
    gw2[nf]  = gow[2048 + cb + nf*16];
    bias[nf] = bj[cb + nf*16];
    sw[nf]   = swr[(size_t)xj*128 + wnh*64 + lr + nf*16];
  }
#pragma unroll
  for (int mf=0;mf<4;++mf)
#pragma unroll
    for (int rr=0;rr<4;++rr){
      const float sx = sxr[rbase + mf*16 + rr];
      float s0=0.f, s1=0.f, s2=0.f;
#pragma unroll
      for (int nf=0;nf<4;++nf){
        float v = sigm((float)acc[mf][nf][rr] * (sx * sw[nf]) + bias[nf]);
        s0 += v*gw0[nf]; s1 += v*gw1[nf]; s2 += v*gw2[nf];
      }
      s0 = rowsum16(s0); s1 = rowsum16(s1); s2 = rowsum16(s2);
      if (lr == 0){
        int lrow = wmh*64 + mf*16 + lq*4 + rr;
        sred[wnh][lrow][0] = s0;
        sred[wnh][lrow][1] = s1;
        sred[wnh][lrow][2] = s2;
      }
    }
  __syncthreads();
  if (tid < 128){
    float* dst = &pacc[((size_t)xj*NB + m0 + tid)*3];
    dst[0] = sred[0][tid][0] + sred[1][tid][0];
    dst[1] = sred[0][tid][1] + sred[1][tid][1];
    dst[2] = sred[0][tid][2] + sred[1][tid][2];
  }
}

// ---- slow/fast as one N=1024 GEMM (W = [W_slow; W_fast] contiguous), K=512
__global__ __launch_bounds__(512, 6) void k_slowfast(const short* __restrict__ A,
     const short* __restrict__ WSF,
     short* __restrict__ SB, short* __restrict__ FB, float* __restrict__ f2sum)
{
  __shared__ __align__(16) short smem[24576];
  __shared__ float f2red[128];
  const int tid = threadIdx.x, wave = tid>>6, lane = tid&63;
  const int wm = wave>>1, wn = wave&1, lr = lane&15, lq = lane>>4;
  int2 r = xcd_remap(8, 2048);
  const int m0 = r.x*256, n0 = r.y*128;
  const bool isfast = (n0 >= 512);
  if (isfast){
    if (tid < 128) f2red[tid] = 0.f;
  }
  f32x4 acc[4][4]; ZERO_ACC(acc);
  gemm256x128<DD>(A, WSF, m0, n0, smem, acc, wave, lane);
  const int rbase = m0 + wm*64 + lq*4;
  const int ccol0 = wn*64 + lr;
  if (!isfast){
#pragma unroll
    for (int ni=0;ni<4;++ni)
#pragma unroll
      for (int mi=0;mi<4;++mi)
#pragma unroll
        for (int rr=0;rr<4;++rr)
          SB[(size_t)(rbase + mi*16 + rr)*DD + (n0 + ccol0 + ni*16)] = f2bf(acc[mi][ni][rr]);
  } else {
#pragma unroll
    for (int ni=0;ni<4;++ni){
      float p = 0.f;
      const int fcol = n0 + ccol0 + ni*16 - 512;
#pragma unroll
      for (int mi=0;mi<4;++mi)
#pragma unroll
        for (int rr=0;rr<4;++rr){
          float fv = acc[mi][ni][rr];
          FB[(size_t)(rbase + mi*16 + rr)*DD + fcol] = f2bf(fv);
          p += fv*fv;
        }
      atomicAdd(&f2red[ccol0 + ni*16], p);
    }
    __syncthreads();
    if (tid < 128) atomicAdd(&f2sum[(n0-512) + tid], f2red[tid]);
  }
}

// ---- hebb = fast^T @ x_cms (TN GEMM via LDS transpose, split-K=32 over B)
__global__ __launch_bounds__(256) void k_hebb(const short* __restrict__ FB,
     const short* __restrict__ XB, float* __restrict__ hebb)
{
  __shared__ __align__(16) short sT[10240];
  const int tid = threadIdx.x, wave = tid>>6, lane = tid&63;
  const int o0 = blockIdx.x*128, d0 = blockIdx.y*128;
  const int bz = blockIdx.z;
  const int tr = tid>>3;
  const int tc = (tid&7)*16;
  const int wm=(wave>>1)*64, wn=(wave&1)*64;
  const int lr = lane & 15, lk = (lane>>4)*8;
  f32x4 acc[4][4];
#pragma unroll
  for (int zi=0;zi<4;++zi)
#pragma unroll
    for (int zj=0;zj<4;++zj) acc[zi][zj] = (f32x4){0.f,0.f,0.f,0.f};
  for (int bb=0; bb<2048; bb+=32){
    const int b0 = bz*2048 + bb;
    __syncthreads();
#pragma unroll
    for (int h=0; h<2; ++h){
      short8 v = *(const short8*)&FB[(size_t)(b0+tr)*DD + o0 + tc + h*8];
#pragma unroll
      for (int j=0;j<8;++j) sT[(tc+h*8+j)*40 + tr] = v[j];
      short8 u = *(const short8*)&XB[(size_t)(b0+tr)*DD + d0 + tc + h*8];
#pragma unroll
      for (int j=0;j<8;++j) sT[5120 + (tc+h*8+j)*40 + tr] = u[j];
    }
    __syncthreads();
    short8 af[4], bf[4];
#pragma unroll
    for (int i=0;i<4;++i) af[i] = *(const short8*)&sT[(wm + i*16 + lr)*40 + lk];
#pragma unroll
    for (int i=0;i<4;++i) bf[i] = *(const short8*)&sT[5120 + (wn + i*16 + lr)*40 + lk];
#pragma unroll
    for (int mi=0;mi<4;++mi)
#pragma unroll
      for (int ni=0;ni<4;++ni)
        acc[mi][ni] = __builtin_amdgcn_mfma_f32_16x16x32_bf16(af[mi], bf[ni], acc[mi][ni], 0,0,0);
  }
  const int rbase = o0 + wm + ((lane>>4)<<2);
  const int cbase = d0 + wn + (lane&15);
#pragma unroll
  for (int mi=0;mi<4;++mi)
#pragma unroll
    for (int ni=0;ni<4;++ni)
#pragma unroll
      for (int r=0;r<4;++r)
        atomicAdd(&hebb[(size_t)(rbase + mi*16 + r)*DD + (cbase + ni*16)], acc[mi][ni][r]);
}

// ---- finalize gates: sum 24 partial slices, sigmoid, stats
__global__ __launch_bounds__(256) void k_gatefin(const float* __restrict__ pacc,
     const float* __restrict__ gob,
     float* __restrict__ sensb, float* __restrict__ gateb, float* __restrict__ sacc)
{
  __shared__ float red[3][256];
  const int tid = threadIdx.x;
  const int row = blockIdx.x*256 + tid;
  float a0=0.f, a1=0.f, a2=0.f;
#pragma unroll
  for (int sidx=0; sidx<24; ++sidx){
    const float* p = &pacc[((size_t)sidx*NB + row)*3];
    a0 += p[0]; a1 += p[1]; a2 += p[2];
  }
  float m = sigm(a0 + gob[0]);
  float s = sigm(a1 + gob[1]);
  float g = sigm(a2 + gob[2]);
  sensb[row] = s; gateb[row] = g;
  red[0][tid]=m; red[1][tid]=s; red[2][tid]=g;
  __syncthreads();
  for (int off=128; off; off>>=1){
    if (tid < off){
      red[0][tid]+=red[0][tid+off];
      red[1][tid]+=red[1][tid+off];
      red[2][tid]+=red[2][tid+off];
    }
    __syncthreads();
  }
  if (tid < 3) atomicAdd(&sacc[tid], red[tid][0]);
}

// ---- merged epilogue: blocks 0..16383 = SiLU-beta/LayerNorm; 16384.. = W_fast
__global__ __launch_bounds__(256) void k_epilogue(const short* __restrict__ SB, const short* __restrict__ FB,
     const float* __restrict__ gate, const float* __restrict__ sens,
     const float* __restrict__ gam, const float* __restrict__ bet, float* __restrict__ out,
     const float* __restrict__ hebb, const float* __restrict__ f2sum, const float* __restrict__ sacc,
     const float* __restrict__ Wf, float* __restrict__ outw, float* __restrict__ outstats)
{
  const int tid = threadIdx.x;
  if (blockIdx.x >= 16384){
    const int idx = (blockIdx.x - 16384)*256 + tid;
    const float inv = 1.f/65536.f;
    const float rate = sacc[0] * inv * 0.1f;
    const int o = idx >> 9;
    float w = Wf[idx];
    float h = hebb[idx] * inv;
    float forget = f2sum[o] * inv * w;
    outw[idx] = w + tanhf(h - forget) * rate;
    if (idx < 3) outstats[idx] = sacc[idx] * inv;
    return;
  }
  const int wave = tid>>6, lane = tid&63;
  const int row = blockIdx.x*4 + wave;
  const float g = gate[row], s = sens[row];
  const float bcoef = 0.5f + 2.0f*s;
  const int c0 = lane*8;
  short8 sv = *(const short8*)&SB[(size_t)row*DD + c0];
  short8 fv = *(const short8*)&FB[(size_t)row*DD + c0];
  float a[8]; float sum = 0.f;
#pragma unroll
  for (int j=0;j<8;++j){
    float c = bf2f(sv[j]) + bf2f(fv[j])*g;
    float av = c * sigm(bcoef*c);
    a[j] = av; sum += av;
  }
  for (int off=32; off; off>>=1) sum += __shfl_down(sum, off);
  sum = __shfl(sum, 0);
  const float mu = sum * (1.f/512.f);
  float vs = 0.f;
#pragma unroll
  for (int j=0;j<8;++j){ float d=a[j]-mu; vs += d*d; }
  for (int off=32; off; off>>=1) vs += __shfl_down(vs, off);
  vs = __shfl(vs, 0);
  const float rstd = rsqrtf(vs*(1.f/512.f) + 1e-5f);
  f32x4 o0, o1;
#pragma unroll
  for (int j=0;j<4;++j) o0[j] = (a[j]-mu)*rstd*gam[c0+j] + bet[c0+j];
#pragma unroll
  for (int j=0;j<4;++j) o1[j] = (a[4+j]-mu)*rstd*gam[c0+4+j] + bet[c0+4+j];
  *(f32x4*)&out[(size_t)row*DD + c0]     = o0;
  *(f32x4*)&out[(size_t)row*DD + c0 + 4] = o1;
}

// ---- merged casts: blocks < 14336 = 4 weight segments (scalar);
//      blocks >= 14336 = x -> outb bf16 (vectorized f32x4)
__global__ __launch_bounds__(256) void k_castall(
     const float* __restrict__ w1, const float* __restrict__ w2,
     const float* __restrict__ wslow, const float* __restrict__ wfast,
     short* __restrict__ wcW1, short* __restrict__ wcW2, short* __restrict__ wcWSF,
     const float* __restrict__ x, short* __restrict__ outb)
{
  const int b = blockIdx.x, t = threadIdx.x;
  if (b >= 14336){
    const int i = (b - 14336)*256 + t;
    f32x4 v = *(const f32x4*)&x[(size_t)i*4];
    short4v bb;
#pragma unroll
    for (int j=0;j<4;++j) bb[j] = f2bf(v[j]);
    *(short4v*)&outb[(size_t)i*4] = bb;
    return;
  }
  const float* src; short* dst; int off;
  if      (b < 6144)  { src=w1;    dst=wcW1;           off=b; }
  else if (b < 12288) { src=w2;    dst=wcW2;           off=b-6144; }
  else if (b < 13312) { src=wslow; dst=wcWSF;          off=b-12288; }
  else                { src=wfast; dst=wcWSF+262144;   off=b-13312; }
  const int i = off*256 + t;
  dst[i] = f2bf(src[i]);
}

extern "C" void kernel_launch(void* const* d_in, const int* in_sizes, int n_in,
                              void* d_out, int out_size, void* d_ws, size_t ws_size,
                              hipStream_t stream)
{
  const float* x    = (const float*)d_in[0];
  const int*   gs   = (const int*)d_in[1];
  const float* w1   = (const float*)d_in[2];
  const float* b1   = (const float*)d_in[3];
  const float* w2   = (const float*)d_in[4];
  const float* b2   = (const float*)d_in[5];
  const float* gmw  = (const float*)d_in[6];
  const float* gmb  = (const float*)d_in[7];
  const float* gsw  = (const float*)d_in[8];
  const float* gsb  = (const float*)d_in[9];
  const float* ggw  = (const float*)d_in[10];
  const float* ggb  = (const float*)d_in[11];
  const float* gow  = (const float*)d_in[12];
  const float* gob  = (const float*)d_in[13];
  const float* wslow= (const float*)d_in[14];
  const float* wfast= (const float*)d_in[15];
  const float* gam  = (const float*)d_in[16];
  const float* bet  = (const float*)d_in[17];

  char* ws = (char*)d_ws;
  char*  x8    = (char*)(ws + 0);             // 32 MB (overlaid later by slowb)
  short* outb  = (short*)(ws + 134217728);    // x_cms bf16 (in-place residual)
  short* hbuf  = (short*)(ws + 201326592);    // H bf16 (CMS); pacc overlays later
  short* wcW1  = (short*)(ws + 335544320);
  short* wcW2  = (short*)(ws + 338690048);
  char*  W8    = (char*)(ws + 341835776);     // 1.5 MB
  short* wcWSF = (short*)(ws + 344981504);    // [W_slow;W_fast] = [1024][512] bf16
  float* hebb  = (float*)(ws + 346030080);
  float* f2sum = (float*)(ws + 347078656);
  float* sacc  = (float*)(ws + 347080704);
  float* sensb = (float*)(ws + 347080960);
  float* gateb = (float*)(ws + 347343104);
  float* sxr   = (float*)(ws + 347605248);
  float* swr   = (float*)(ws + 347867392);
  float* pacc  = (float*)(ws + 201326592);    // overlays hbuf (dead after CMS)
  short* slowb = (short*)(ws + 0);            // overlays x8 (dead after k_gates)
  short* fastb = (short*)(ws + 67108864);

  float* o_ln = (float*)d_out;
  float* o_wf = o_ln + (size_t)NB*DD;
  float* o_st = o_wf + 262144;

  hipMemsetAsync(hebb, 0, 1048576, stream);
  hipMemsetAsync(f2sum, 0, 2048, stream);
  hipMemsetAsync(sacc, 0, 256, stream);

  k_castall<<<dim3(47104),256,0,stream>>>(w1, w2, wslow, wfast,
                                          wcW1, wcW2, wcWSF, x, outb);
  k_quantw<<<dim3(768),256,0,stream>>>(gmw, gsw, ggw, W8, swr);

  const int freqs[3] = {1,4,16};
  for (int lv=0; lv<3; ++lv){
    k_gemm_h  <<<dim3(8,256),512,0,stream>>>(gs, freqs[lv], outb, wcW1 + (size_t)lv*524288, b1 + lv*HH, hbuf);
    k_gemm_res<<<dim3(4,256),512,0,stream>>>(gs, freqs[lv], hbuf, wcW2 + (size_t)lv*524288, b2 + lv*DD, outb);
  }

  k_quantx <<<dim3(16384),256,0,stream>>>(outb, x8, sxr);
  k_gates  <<<dim3(24,512),256,0,stream>>>(x8, W8, sxr, swr, gmb, gsb, ggb, gow, pacc);
  k_gatefin<<<dim3(256),256,0,stream>>>(pacc, gob, sensb, gateb, sacc);
  k_slowfast<<<dim3(8,256),512,0,stream>>>(outb, wcWSF, slowb, fastb, f2sum);
  k_hebb   <<<dim3(4,4,32),256,0,stream>>>(fastb, outb, hebb);
  k_epilogue<<<dim3(17408),256,0,stream>>>(slowb, fastb, gateb, sensb, gam, bet, o_ln,
                                           hebb, f2sum, sacc, wfast, o_wf, o_st);
}

// Round 13
// 1217.837 us; speedup vs baseline: 5.5275x; 5.5275x over previous
//
#include <hip/hip_runtime.h>
#include <hip/hip_bf16.h>
#include <cstdint>
#include <cstddef>

#define NB 65536
#define DD 512
#define HH 1024

typedef __attribute__((ext_vector_type(8))) short short8;
typedef __attribute__((ext_vector_type(4))) short short4v;
typedef __attribute__((ext_vector_type(4))) float f32x4;
typedef __attribute__((ext_vector_type(4))) int int4v;

__device__ __forceinline__ float bf2f(short s){
  union { float f; unsigned u; } v; v.u = ((unsigned)(unsigned short)s) << 16; return v.f;
}
__device__ __forceinline__ short f2bf(float f){
  union { float f; unsigned u; } v; v.f = f;
  unsigned u = v.u;
  u += 0x7FFFu + ((u >> 16) & 1u);
  return (short)(u >> 16);
}
__device__ __forceinline__ float sigm(float x){ return 1.0f / (1.0f + __expf(-x)); }

// sum over the 16 lanes of a DPP row; result in all lanes
__device__ __forceinline__ float rowsum16(float v){
  int x;
  x = __builtin_amdgcn_update_dpp(0, __float_as_int(v), 0x128, 0xF, 0xF, true); v += __int_as_float(x); // ror:8
  x = __builtin_amdgcn_update_dpp(0, __float_as_int(v), 0x124, 0xF, 0xF, true); v += __int_as_float(x); // ror:4
  x = __builtin_amdgcn_update_dpp(0, __float_as_int(v), 0x122, 0xF, 0xF, true); v += __int_as_float(x); // ror:2
  x = __builtin_amdgcn_update_dpp(0, __float_as_int(v), 0x121, 0xF, 0xF, true); v += __int_as_float(x); // ror:1
  return v;
}

// XCD-bijective remap: each XCD gets a contiguous m-range; the NX (n/j)-blocks
// sharing one A-tile run consecutively on the same XCD -> A-tile L2 reuse.
__device__ __forceinline__ int2 xcd_remap(int NX, int G){
  int flat = blockIdx.y*NX + blockIdx.x;
  int l = (flat & 7)*(G>>3) + (flat>>3);
  return make_int2(l / NX, l % NX);   // (m-tile, xj)
}

#define GLL(srcp, dstp) \
  __builtin_amdgcn_global_load_lds((const __attribute__((address_space(1))) void*)(srcp), \
                                   (__attribute__((address_space(3))) void*)(dstp), 16, 0, 0)

// ---- swizzled stage of a 128x32 bf16 tile into LDS as [64 phys rows][128B],
// logical rows 0-63 in granules 0-3, rows 64-127 in granules 4-7, with
// granule XOR (p&7).  Linear GLL dest; swizzle folded into global source.
__device__ __forceinline__ void stage128x32s(const short* __restrict__ g, int row0, int ldk, int k0,
                                             short* lds_base, int wave, int lane){
  const int pl = lane>>3, Gp = lane&7;
  const int Gl = Gp ^ pl;                  // logical granule
  const int rconst = pl + ((Gl>>2)<<6);    // logical row offset (within tile)
  const int kg = (Gl&3)*8;                 // k offset within 32-col tile
#pragma unroll
  for (int i = 0; i < 2; ++i){
    int c = wave*2 + i;                    // chunk 0..7 = 1024B each
    const short* src = g + (size_t)(row0 + c*8 + rconst)*(size_t)ldk + (size_t)(k0 + kg);
    GLL(src, lds_base + c*512);
  }
}

// ---- i8 variant: 128x64 i8 tile (same 8 KB byte-shape), ldk fixed 512 B
__device__ __forceinline__ void stage128x64q(const char* __restrict__ g, int k0B,
                                             char* lds_base, int wave, int lane){
  const int pl = lane>>3, Gp = lane&7;
  const int Gl = Gp ^ pl;
  const int rconst = pl + ((Gl>>2)<<6);
  const int kg = (Gl&3)*16;
#pragma unroll
  for (int i = 0; i < 2; ++i){
    int c = wave*2 + i;
    const char* src = g + (size_t)(c*8 + rconst)*512 + (size_t)(k0B + kg);
    GLL(src, lds_base + c*1024);
  }
}

// ============================================================================
// 128x128-tile NT GEMM core (m97-class): BK=32, double-buffered LDS (32 KB),
// 4 waves, per-wave 64x64 output acc[4][4]; vmcnt(0)+barrier per K-step hidden
// by 4 blocks/CU TLP.  [64 phys rows][128B] granule^(row&7) swizzle (2-way).
// ============================================================================
template<int KTOT>
__device__ __forceinline__ void gemm128(const short* __restrict__ A, const short* __restrict__ W,
        int m0, int n0, short* smem, f32x4 acc[4][4], int wave, int lane)
{
  const int lr = lane & 15, lq = lane>>4;
  const int hiA = wave>>1, hiB = wave&1;
  int aOff[4], bOff[4];
#pragma unroll
  for (int i=0;i<4;++i){
    int pa = i*16 + lr;                    // physical row (= logical row & 63)
    aOff[i] =        pa*64 + (((hiA*4+lq) ^ (pa&7))<<3);
    bOff[i] = 4096 + pa*64 + (((hiB*4+lq) ^ (pa&7))<<3);
  }
  stage128x32s(A, m0, KTOT, 0, smem,        wave, lane);
  stage128x32s(W, n0, KTOT, 0, smem + 4096, wave, lane);
  asm volatile("s_waitcnt vmcnt(0)" ::: "memory");
  __builtin_amdgcn_s_barrier();
  int cur = 0;
#pragma unroll
  for (int k0 = 0; k0 < KTOT; k0 += 32){
    short* buf  = smem + cur*8192;
    short* nbuf = smem + (cur^1)*8192;
    if (k0 + 32 < KTOT){
      stage128x32s(A, m0, KTOT, k0+32, nbuf,        wave, lane);
      stage128x32s(W, n0, KTOT, k0+32, nbuf + 4096, wave, lane);
    }
    short8 af[4], bf[4];
#pragma unroll
    for (int i=0;i<4;++i) af[i] = *(const short8*)&buf[aOff[i]];
#pragma unroll
    for (int i=0;i<4;++i) bf[i] = *(const short8*)&buf[bOff[i]];
    __builtin_amdgcn_s_setprio(1);
#pragma unroll
    for (int mi=0;mi<4;++mi)
#pragma unroll
      for (int ni=0;ni<4;++ni)
        acc[mi][ni] = __builtin_amdgcn_mfma_f32_16x16x32_bf16(af[mi], bf[ni], acc[mi][ni], 0, 0, 0);
    __builtin_amdgcn_s_setprio(0);
    asm volatile("s_waitcnt vmcnt(0)" ::: "memory");
    __builtin_amdgcn_s_barrier();
    cur ^= 1;
  }
}

#define ZERO_ACC(acc) \
  _Pragma("unroll") for (int zi=0;zi<4;++zi) _Pragma("unroll") for (int zj=0;zj<4;++zj) \
    acc[zi][zj] = (f32x4){0.f,0.f,0.f,0.f};

// ---- CMS level GEMM1: H = relu(out @ w1^T + b1), bf16 out. N=1024, K=512
__global__ __launch_bounds__(256, 4) void k_gemm_h(const int* __restrict__ gs, int freq,
     const short* __restrict__ A, const short* __restrict__ W1, const float* __restrict__ b1,
     short* __restrict__ Hout)
{
  if (gs[0] % freq) return;
  __shared__ __align__(16) short smem[16384];
  const int tid = threadIdx.x, wave = tid>>6, lane = tid&63;
  int2 r = xcd_remap(8, 4096);
  const int m0 = r.x*128, n0 = r.y*128;
  f32x4 acc[4][4]; ZERO_ACC(acc);
  gemm128<DD>(A, W1, m0, n0, smem, acc, wave, lane);
  const int wm=(wave>>1)*64, wn=(wave&1)*64;
  const int rbase = m0 + wm + ((lane>>4)<<2);
  const int cbase = n0 + wn + (lane&15);
#pragma unroll
  for (int ni=0;ni<4;++ni){
    const float bias = b1[cbase + ni*16];
#pragma unroll
    for (int mi=0;mi<4;++mi)
#pragma unroll
      for (int rr=0;rr<4;++rr){
        float v = acc[mi][ni][rr] + bias;
        v = v > 0.f ? v : 0.f;
        Hout[(size_t)(rbase + mi*16 + rr)*HH + (cbase + ni*16)] = f2bf(v);
      }
  }
}

// ---- CMS level GEMM2: out += H @ w2^T + b2, bf16 in-place residual. N=512, K=1024
__global__ __launch_bounds__(256, 4) void k_gemm_res(const int* __restrict__ gs, int freq,
     const short* __restrict__ Hb, const short* __restrict__ W2, const float* __restrict__ b2,
     short* __restrict__ outb)
{
  if (gs[0] % freq) return;
  __shared__ __align__(16) short smem[16384];
  const int tid = threadIdx.x, wave = tid>>6, lane = tid&63;
  int2 r = xcd_remap(4, 2048);
  const int m0 = r.x*128, n0 = r.y*128;
  f32x4 acc[4][4]; ZERO_ACC(acc);
  gemm128<HH>(Hb, W2, m0, n0, smem, acc, wave, lane);
  const int wm=(wave>>1)*64, wn=(wave&1)*64;
  const int rbase = m0 + wm + ((lane>>4)<<2);
  const int cbase = n0 + wn + (lane&15);
#pragma unroll
  for (int ni=0;ni<4;++ni){
    const float bias = b2[cbase + ni*16];
#pragma unroll
    for (int mi=0;mi<4;++mi)
#pragma unroll
      for (int rr=0;rr<4;++rr){
        size_t off = (size_t)(rbase + mi*16 + rr)*DD + (cbase + ni*16);
        float v = acc[mi][ni][rr] + bias + bf2f(outb[off]);
        outb[off] = f2bf(v);
      }
  }
}

// ---- per-row int8 quantization of x_cms (bf16 -> i8 + row scale)
__global__ __launch_bounds__(256) void k_quantx(const short* __restrict__ outb,
     char* __restrict__ x8, float* __restrict__ sxr)
{
  const int tid = threadIdx.x, wave = tid>>6, lane = tid&63;
  const int row = blockIdx.x*4 + wave;
  short8 v = *(const short8*)&outb[(size_t)row*DD + lane*8];
  float f[8]; float m = 0.f;
#pragma unroll
  for (int j=0;j<8;++j){ f[j] = bf2f(v[j]); m = fmaxf(m, fabsf(f[j])); }
#pragma unroll
  for (int off=32; off; off>>=1) m = fmaxf(m, __shfl_xor(m, off));
  m = fmaxf(m, 1e-20f);
  const float inv = 127.0f / m;
  unsigned lo=0, hi=0;
#pragma unroll
  for (int j=0;j<4;++j){ int q=(int)rintf(f[j]*inv); q=q>127?127:(q<-127?-127:q); lo |= ((unsigned)(q&255))<<(8*j); }
#pragma unroll
  for (int j=0;j<4;++j){ int q=(int)rintf(f[4+j]*inv); q=q>127?127:(q<-127?-127:q); hi |= ((unsigned)(q&255))<<(8*j); }
  int2 w; w.x=(int)lo; w.y=(int)hi;
  *(int2*)&x8[(size_t)row*DD + lane*8] = w;
  if (lane==0) sxr[row] = m * (1.0f/127.0f);
}

// ---- per-row int8 quantization of the 3 gate weights (fp32 -> i8 + scale)
__global__ __launch_bounds__(256) void k_quantw(const float* __restrict__ gmw,
     const float* __restrict__ gsw, const float* __restrict__ ggw,
     char* __restrict__ W8, float* __restrict__ swr)
{
  const int tid = threadIdx.x, wave = tid>>6, lane = tid&63;
  const int row = blockIdx.x*4 + wave;      // 0..3071
  const int j = row >> 10;
  const float* src = (j==0?gmw:(j==1?gsw:ggw)) + (size_t)(row&1023)*DD + lane*8;
  f32x4 a = *(const f32x4*)&src[0];
  f32x4 b = *(const f32x4*)&src[4];
  float f[8] = {a[0],a[1],a[2],a[3],b[0],b[1],b[2],b[3]};
  float m = 0.f;
#pragma unroll
  for (int k=0;k<8;++k) m = fmaxf(m, fabsf(f[k]));
#pragma unroll
  for (int off=32; off; off>>=1) m = fmaxf(m, __shfl_xor(m, off));
  m = fmaxf(m, 1e-20f);
  const float inv = 127.0f / m;
  unsigned lo=0, hi=0;
#pragma unroll
  for (int k=0;k<4;++k){ int q=(int)rintf(f[k]*inv); q=q>127?127:(q<-127?-127:q); lo |= ((unsigned)(q&255))<<(8*k); }
#pragma unroll
  for (int k=0;k<4;++k){ int q=(int)rintf(f[4+k]*inv); q=q>127?127:(q<-127?-127:q); hi |= ((unsigned)(q&255))<<(8*k); }
  int2 w; w.x=(int)lo; w.y=(int)hi;
  *(int2*)&W8[(size_t)row*DD + lane*8] = w;
  if (lane==0) swr[row] = m * (1.0f/127.0f);
}

// ---- gates fused with gate-out, INT8 core (mfma_i32_16x16x64_i8, 2x bf16 rate).
// Same m97+TLP structure; BK=64 i8 (identical 8 KB staging byte-shape);
// per-row scales applied in epilogue; partials pacc[24][65536][3].
__global__ __launch_bounds__(256, 4) void k_gates(const char* __restrict__ X8, const char* __restrict__ W8,
     const float* __restrict__ sxr, const float* __restrict__ swr,
     const float* __restrict__ bm, const float* __restrict__ bs, const float* __restrict__ bg,
     const float* __restrict__ gow, float* __restrict__ pacc)
{
  __shared__ __align__(16) char smemc[32768];
  __shared__ float sred[2][128][3];
  const int tid = threadIdx.x, wave = tid>>6, lane = tid&63;
  const int wmh = wave>>1, wnh = wave&1, lr = lane&15, lq = lane>>4;
  int2 r = xcd_remap(24, 12288);
  const int m0 = r.x*128, xj = r.y;
  const int j = xj >> 3;
  const int n0 = (xj & 7)*128;
  int aOff[4], bOff[4];
#pragma unroll
  for (int i=0;i<4;++i){
    int pa = i*16 + lr;
    aOff[i] =        pa*128 + (((wmh*4+lq) ^ (pa&7))<<4);
    bOff[i] = 8192 + pa*128 + (((wnh*4+lq) ^ (pa&7))<<4);
  }
  const char* aS = X8 + (size_t)m0*DD;
  const char* bS = W8 + (size_t)xj*128*DD;
  int4v acc[4][4];
#pragma unroll
  for (int zi=0;zi<4;++zi)
#pragma unroll
    for (int zj=0;zj<4;++zj) acc[zi][zj] = (int4v){0,0,0,0};

  stage128x64q(aS, 0, smemc,        wave, lane);
  stage128x64q(bS, 0, smemc + 8192, wave, lane);
  asm volatile("s_waitcnt vmcnt(0)" ::: "memory");
  __builtin_amdgcn_s_barrier();
  int cur = 0;
#pragma unroll
  for (int kt = 0; kt < 8; ++kt){
    char* buf  = smemc + cur*16384;
    char* nbuf = smemc + (cur^1)*16384;
    if (kt + 1 < 8){
      stage128x64q(aS, (kt+1)*64, nbuf,        wave, lane);
      stage128x64q(bS, (kt+1)*64, nbuf + 8192, wave, lane);
    }
    int4v af[4], bf[4];
#pragma unroll
    for (int i=0;i<4;++i) af[i] = *(const int4v*)&buf[aOff[i]];
#pragma unroll
    for (int i=0;i<4;++i) bf[i] = *(const int4v*)&buf[bOff[i]];
    __builtin_amdgcn_s_setprio(1);
#pragma unroll
    for (int mi=0;mi<4;++mi)
#pragma unroll
      for (int ni=0;ni<4;++ni)
        acc[mi][ni] = __builtin_amdgcn_mfma_i32_16x16x64_i8(af[mi], bf[ni], acc[mi][ni], 0, 0, 0);
    __builtin_amdgcn_s_setprio(0);
    asm volatile("s_waitcnt vmcnt(0)" ::: "memory");
    __builtin_amdgcn_s_barrier();
    cur ^= 1;
  }

  const int cb = n0 + wnh*64 + lr;
  const int rbase = m0 + wmh*64 + lq*4;
  const float* bj = (j==0) ? bm : ((j==1) ? bs : bg);
  float gw0[4], gw1[4], gw2[4], bias[4], sw[4];
#pragma unroll
  for (int nf=0;nf<4;++nf){
    gw0[nf]  = gow[cb + nf*16];
    gw1[nf]  = gow[1024 + cb + nf*16];
    gw2[nf]  = gow[2048 + cb + nf*16];
    bias[nf] = bj[cb + nf*16];
    sw[nf]   = swr[(size_t)xj*128 + wnh*64 + lr + nf*16];
  }
#pragma unroll
  for (int mf=0;mf<4;++mf)
#pragma unroll
    for (int rr=0;rr<4;++rr){
      const float sx = sxr[rbase + mf*16 + rr];
      float s0=0.f, s1=0.f, s2=0.f;
#pragma unroll
      for (int nf=0;nf<4;++nf){
        float v = sigm((float)acc[mf][nf][rr] * (sx * sw[nf]) + bias[nf]);
        s0 += v*gw0[nf]; s1 += v*gw1[nf]; s2 += v*gw2[nf];
      }
      s0 = rowsum16(s0); s1 = rowsum16(s1); s2 = rowsum16(s2);
      if (lr == 0){
        int lrow = wmh*64 + mf*16 + lq*4 + rr;
        sred[wnh][lrow][0] = s0;
        sred[wnh][lrow][1] = s1;
        sred[wnh][lrow][2] = s2;
      }
    }
  __syncthreads();
  if (tid < 128){
    float* dst = &pacc[((size_t)xj*NB + m0 + tid)*3];
    dst[0] = sred[0][tid][0] + sred[1][tid][0];
    dst[1] = sred[0][tid][1] + sred[1][tid][1];
    dst[2] = sred[0][tid][2] + sred[1][tid][2];
  }
}

// ---- slow/fast as one N=1024 GEMM (W = [W_slow; W_fast] contiguous), K=512
__global__ __launch_bounds__(256, 4) void k_slowfast(const short* __restrict__ A,
     const short* __restrict__ WSF,
     short* __restrict__ SB, short* __restrict__ FB, float* __restrict__ f2sum)
{
  __shared__ __align__(16) short smem[16384];
  __shared__ float f2red[128];
  const int tid = threadIdx.x, wave = tid>>6, lane = tid&63;
  int2 r = xcd_remap(8, 4096);
  const int m0 = r.x*128, n0 = r.y*128;
  const bool isfast = (n0 >= 512);
  if (isfast){
    if (tid < 128) f2red[tid] = 0.f;
  }
  f32x4 acc[4][4]; ZERO_ACC(acc);
  gemm128<DD>(A, WSF, m0, n0, smem, acc, wave, lane);
  const int wm=(wave>>1)*64, wn=(wave&1)*64;
  const int rbase = m0 + wm + ((lane>>4)<<2);
  const int ccol0 = wn + (lane&15);
  if (!isfast){
#pragma unroll
    for (int ni=0;ni<4;++ni)
#pragma unroll
      for (int mi=0;mi<4;++mi)
#pragma unroll
        for (int rr=0;rr<4;++rr)
          SB[(size_t)(rbase + mi*16 + rr)*DD + (n0 + ccol0 + ni*16)] = f2bf(acc[mi][ni][rr]);
  } else {
#pragma unroll
    for (int ni=0;ni<4;++ni){
      float p = 0.f;
      const int fcol = n0 + ccol0 + ni*16 - 512;
#pragma unroll
      for (int mi=0;mi<4;++mi)
#pragma unroll
        for (int rr=0;rr<4;++rr){
          float fv = acc[mi][ni][rr];
          FB[(size_t)(rbase + mi*16 + rr)*DD + fcol] = f2bf(fv);
          p += fv*fv;
        }
      atomicAdd(&f2red[ccol0 + ni*16], p);
    }
    __syncthreads();
    if (tid < 128) atomicAdd(&f2sum[(n0-512) + tid], f2red[tid]);
  }
}

// ---- hebb = fast^T @ x_cms (TN GEMM via LDS transpose, split-K=32 over B)
__global__ __launch_bounds__(256) void k_hebb(const short* __restrict__ FB,
     const short* __restrict__ XB, float* __restrict__ hebb)
{
  __shared__ __align__(16) short sT[10240];
  const int tid = threadIdx.x, wave = tid>>6, lane = tid&63;
  const int o0 = blockIdx.x*128, d0 = blockIdx.y*128;
  const int bz = blockIdx.z;
  const int tr = tid>>3;
  const int tc = (tid&7)*16;
  const int wm=(wave>>1)*64, wn=(wave&1)*64;
  const int lr = lane & 15, lk = (lane>>4)*8;
  f32x4 acc[4][4];
#pragma unroll
  for (int zi=0;zi<4;++zi)
#pragma unroll
    for (int zj=0;zj<4;++zj) acc[zi][zj] = (f32x4){0.f,0.f,0.f,0.f};
  for (int bb=0; bb<2048; bb+=32){
    const int b0 = bz*2048 + bb;
    __syncthreads();
#pragma unroll
    for (int h=0; h<2; ++h){
      short8 v = *(const short8*)&FB[(size_t)(b0+tr)*DD + o0 + tc + h*8];
#pragma unroll
      for (int j=0;j<8;++j) sT[(tc+h*8+j)*40 + tr] = v[j];
      short8 u = *(const short8*)&XB[(size_t)(b0+tr)*DD + d0 + tc + h*8];
#pragma unroll
      for (int j=0;j<8;++j) sT[5120 + (tc+h*8+j)*40 + tr] = u[j];
    }
    __syncthreads();
    short8 af[4], bf[4];
#pragma unroll
    for (int i=0;i<4;++i) af[i] = *(const short8*)&sT[(wm + i*16 + lr)*40 + lk];
#pragma unroll
    for (int i=0;i<4;++i) bf[i] = *(const short8*)&sT[5120 + (wn + i*16 + lr)*40 + lk];
#pragma unroll
    for (int mi=0;mi<4;++mi)
#pragma unroll
      for (int ni=0;ni<4;++ni)
        acc[mi][ni] = __builtin_amdgcn_mfma_f32_16x16x32_bf16(af[mi], bf[ni], acc[mi][ni], 0,0,0);
  }
  const int rbase = o0 + wm + ((lane>>4)<<2);
  const int cbase = d0 + wn + (lane&15);
#pragma unroll
  for (int mi=0;mi<4;++mi)
#pragma unroll
    for (int ni=0;ni<4;++ni)
#pragma unroll
      for (int r=0;r<4;++r)
        atomicAdd(&hebb[(size_t)(rbase + mi*16 + r)*DD + (cbase + ni*16)], acc[mi][ni][r]);
}

// ---- finalize gates: sum 24 partial slices, sigmoid, stats
__global__ __launch_bounds__(256) void k_gatefin(const float* __restrict__ pacc,
     const float* __restrict__ gob,
     float* __restrict__ sensb, float* __restrict__ gateb, float* __restrict__ sacc)
{
  __shared__ float red[3][256];
  const int tid = threadIdx.x;
  const int row = blockIdx.x*256 + tid;
  float a0=0.f, a1=0.f, a2=0.f;
#pragma unroll
  for (int sidx=0; sidx<24; ++sidx){
    const float* p = &pacc[((size_t)sidx*NB + row)*3];
    a0 += p[0]; a1 += p[1]; a2 += p[2];
  }
  float m = sigm(a0 + gob[0]);
  float s = sigm(a1 + gob[1]);
  float g = sigm(a2 + gob[2]);
  sensb[row] = s; gateb[row] = g;
  red[0][tid]=m; red[1][tid]=s; red[2][tid]=g;
  __syncthreads();
  for (int off=128; off; off>>=1){
    if (tid < off){
      red[0][tid]+=red[0][tid+off];
      red[1][tid]+=red[1][tid+off];
      red[2][tid]+=red[2][tid+off];
    }
    __syncthreads();
  }
  if (tid < 3) atomicAdd(&sacc[tid], red[tid][0]);
}

// ---- merged epilogue: blocks 0..16383 = SiLU-beta/LayerNorm; 16384.. = W_fast
__global__ __launch_bounds__(256) void k_epilogue(const short* __restrict__ SB, const short* __restrict__ FB,
     const float* __restrict__ gate, const float* __restrict__ sens,
     const float* __restrict__ gam, const float* __restrict__ bet, float* __restrict__ out,
     const float* __restrict__ hebb, const float* __restrict__ f2sum, const float* __restrict__ sacc,
     const float* __restrict__ Wf, float* __restrict__ outw, float* __restrict__ outstats)
{
  const int tid = threadIdx.x;
  if (blockIdx.x >= 16384){
    const int idx = (blockIdx.x - 16384)*256 + tid;
    const float inv = 1.f/65536.f;
    const float rate = sacc[0] * inv * 0.1f;
    const int o = idx >> 9;
    float w = Wf[idx];
    float h = hebb[idx] * inv;
    float forget = f2sum[o] * inv * w;
    outw[idx] = w + tanhf(h - forget) * rate;
    if (idx < 3) outstats[idx] = sacc[idx] * inv;
    return;
  }
  const int wave = tid>>6, lane = tid&63;
  const int row = blockIdx.x*4 + wave;
  const float g = gate[row], s = sens[row];
  const float bcoef = 0.5f + 2.0f*s;
  const int c0 = lane*8;
  short8 sv = *(const short8*)&SB[(size_t)row*DD + c0];
  short8 fv = *(const short8*)&FB[(size_t)row*DD + c0];
  float a[8]; float sum = 0.f;
#pragma unroll
  for (int j=0;j<8;++j){
    float c = bf2f(sv[j]) + bf2f(fv[j])*g;
    float av = c * sigm(bcoef*c);
    a[j] = av; sum += av;
  }
  for (int off=32; off; off>>=1) sum += __shfl_down(sum, off);
  sum = __shfl(sum, 0);
  const float mu = sum * (1.f/512.f);
  float vs = 0.f;
#pragma unroll
  for (int j=0;j<8;++j){ float d=a[j]-mu; vs += d*d; }
  for (int off=32; off; off>>=1) vs += __shfl_down(vs, off);
  vs = __shfl(vs, 0);
  const float rstd = rsqrtf(vs*(1.f/512.f) + 1e-5f);
  f32x4 o0, o1;
#pragma unroll
  for (int j=0;j<4;++j) o0[j] = (a[j]-mu)*rstd*gam[c0+j] + bet[c0+j];
#pragma unroll
  for (int j=0;j<4;++j) o1[j] = (a[4+j]-mu)*rstd*gam[c0+4+j] + bet[c0+4+j];
  *(f32x4*)&out[(size_t)row*DD + c0]     = o0;
  *(f32x4*)&out[(size_t)row*DD + c0 + 4] = o1;
}

// ---- merged casts: blocks < 14336 = 4 weight segments (scalar);
//      blocks >= 14336 = x -> outb bf16 (vectorized f32x4)
__global__ __launch_bounds__(256) void k_castall(
     const float* __restrict__ w1, const float* __restrict__ w2,
     const float* __restrict__ wslow, const float* __restrict__ wfast,
     short* __restrict__ wcW1, short* __restrict__ wcW2, short* __restrict__ wcWSF,
     const float* __restrict__ x, short* __restrict__ outb)
{
  const int b = blockIdx.x, t = threadIdx.x;
  if (b >= 14336){
    const int i = (b - 14336)*256 + t;
    f32x4 v = *(const f32x4*)&x[(size_t)i*4];
    short4v bb;
#pragma unroll
    for (int j=0;j<4;++j) bb[j] = f2bf(v[j]);
    *(short4v*)&outb[(size_t)i*4] = bb;
    return;
  }
  const float* src; short* dst; int off;
  if      (b < 6144)  { src=w1;    dst=wcW1;           off=b; }
  else if (b < 12288) { src=w2;    dst=wcW2;           off=b-6144; }
  else if (b < 13312) { src=wslow; dst=wcWSF;          off=b-12288; }
  else                { src=wfast; dst=wcWSF+262144;   off=b-13312; }
  const int i = off*256 + t;
  dst[i] = f2bf(src[i]);
}

extern "C" void kernel_launch(void* const* d_in, const int* in_sizes, int n_in,
                              void* d_out, int out_size, void* d_ws, size_t ws_size,
                              hipStream_t stream)
{
  const float* x    = (const float*)d_in[0];
  const int*   gs   = (const int*)d_in[1];
  const float* w1   = (const float*)d_in[2];
  const float* b1   = (const float*)d_in[3];
  const float* w2   = (const float*)d_in[4];
  const float* b2   = (const float*)d_in[5];
  const float* gmw  = (const float*)d_in[6];
  const float* gmb  = (const float*)d_in[7];
  const float* gsw  = (const float*)d_in[8];
  const float* gsb  = (const float*)d_in[9];
  const float* ggw  = (const float*)d_in[10];
  const float* ggb  = (const float*)d_in[11];
  const float* gow  = (const float*)d_in[12];
  const float* gob  = (const float*)d_in[13];
  const float* wslow= (const float*)d_in[14];
  const float* wfast= (const float*)d_in[15];
  const float* gam  = (const float*)d_in[16];
  const float* bet  = (const float*)d_in[17];

  char* ws = (char*)d_ws;
  char*  x8    = (char*)(ws + 0);             // 32 MB (overlaid later by slowb)
  short* outb  = (short*)(ws + 134217728);    // x_cms bf16 (in-place residual)
  short* hbuf  = (short*)(ws + 201326592);    // H bf16 (CMS); pacc overlays later
  short* wcW1  = (short*)(ws + 335544320);
  short* wcW2  = (short*)(ws + 338690048);
  char*  W8    = (char*)(ws + 341835776);     // 1.5 MB
  short* wcWSF = (short*)(ws + 344981504);    // [W_slow;W_fast] = [1024][512] bf16
  float* hebb  = (float*)(ws + 346030080);
  float* f2sum = (float*)(ws + 347078656);
  float* sacc  = (float*)(ws + 347080704);
  float* sensb = (float*)(ws + 347080960);
  float* gateb = (float*)(ws + 347343104);
  float* sxr   = (float*)(ws + 347605248);
  float* swr   = (float*)(ws + 347867392);
  float* pacc  = (float*)(ws + 201326592);    // overlays hbuf (dead after CMS)
  short* slowb = (short*)(ws + 0);            // overlays x8 (dead after k_gates)
  short* fastb = (short*)(ws + 67108864);

  float* o_ln = (float*)d_out;
  float* o_wf = o_ln + (size_t)NB*DD;
  float* o_st = o_wf + 262144;

  hipMemsetAsync(hebb, 0, 1048576, stream);
  hipMemsetAsync(f2sum, 0, 2048, stream);
  hipMemsetAsync(sacc, 0, 256, stream);

  k_castall<<<dim3(47104),256,0,stream>>>(w1, w2, wslow, wfast,
                                          wcW1, wcW2, wcWSF, x, outb);
  k_quantw<<<dim3(768),256,0,stream>>>(gmw, gsw, ggw, W8, swr);

  const int freqs[3] = {1,4,16};
  for (int lv=0; lv<3; ++lv){
    k_gemm_h  <<<dim3(8,512),256,0,stream>>>(gs, freqs[lv], outb, wcW1 + (size_t)lv*524288, b1 + lv*HH, hbuf);
    k_gemm_res<<<dim3(4,512),256,0,stream>>>(gs, freqs[lv], hbuf, wcW2 + (size_t)lv*524288, b2 + lv*DD, outb);
  }

  k_quantx <<<dim3(16384),256,0,stream>>>(outb, x8, sxr);
  k_gates  <<<dim3(24,512),256,0,stream>>>(x8, W8, sxr, swr, gmb, gsb, ggb, gow, pacc);
  k_gatefin<<<dim3(256),256,0,stream>>>(pacc, gob, sensb, gateb, sacc);
  k_slowfast<<<dim3(8,512),256,0,stream>>>(outb, wcWSF, slowb, fastb, f2sum);
  k_hebb   <<<dim3(4,4,32),256,0,stream>>>(fastb, outb, hebb);
  k_epilogue<<<dim3(17408),256,0,stream>>>(slowb, fastb, gateb, sensb, gam, bet, o_ln,
                                           hebb, f2sum, sacc, wfast, o_wf, o_st);
}